// Round 9
// baseline (424.888 us; speedup 1.0000x reference)
//
#include <hip/hip_runtime.h>

typedef __bf16 bf16;
typedef __bf16 bf16x4 __attribute__((ext_vector_type(4)));
typedef __bf16 bf16x8 __attribute__((ext_vector_type(8)));
typedef float  f32x4  __attribute__((ext_vector_type(4)));

// Problem constants
#define NB    16384      // batch
#define NOBS  568
#define NH    256
#define NAG   19         // N_OTHER

// ws byte offsets (all 16B aligned)
#define OFF_WT_MU    0u          // [256][576] bf16 (flat [n][kpad])
#define OFF_WT_VAR   294912u     // [256][576]
#define OFF_WT_SELF  589824u     // [256][64]
#define OFF_WT_OTHER 622592u     // [256][32]  (chunk-major == flat at K=32)
#define OFF_WT_Q     638976u     // [256][256] flat
#define OFF_WT_K     770048u     // CHUNK-MAJOR [8][256][32]
#define OFF_WT_V1    901120u     // CHUNK-MAJOR [8][256][32]
#define OFF_WT_V2    1032192u    // flat
#define OFF_WT_A1    1163264u    // flat
#define OFF_WT_A2    1294336u    // flat
#define OFF_Z        1425408u    // [16384][256] bf16
#define OFF_SELF     9814016u
#define OFF_Q        18202624u
#define OFF_SV       26591232u   // bf16 (includes b_v)
#define OFF_H        34979840u

static __device__ __forceinline__ unsigned short bfbits(float v) {
  bf16 b = (bf16)v;
  union { bf16 b; unsigned short u; } cvt; cvt.b = b; return cvt.u;
}

// ---------------------------------------------------------------------------
// Weight prep (exact round-8 version).
// ---------------------------------------------------------------------------
__global__ __launch_bounds__(256) void wprep(
    const float* __restrict__ Wmu, const float* __restrict__ Wvar,
    const float* __restrict__ Wself, const float* __restrict__ Wother,
    const float* __restrict__ Wq, const float* __restrict__ Wk,
    const float* __restrict__ Wv, const float* __restrict__ Wa, char* wsb)
{
  const float* src; bf16* dst; int K, Kp; bool chunked = false;
  switch (blockIdx.y) {
    case 0: src = Wmu;        dst = (bf16*)(wsb + OFF_WT_MU);    K = 568; Kp = 576; break;
    case 1: src = Wvar;       dst = (bf16*)(wsb + OFF_WT_VAR);   K = 568; Kp = 576; break;
    case 2: src = Wself;      dst = (bf16*)(wsb + OFF_WT_SELF);  K = 36;  Kp = 64;  break;
    case 3: src = Wother;     dst = (bf16*)(wsb + OFF_WT_OTHER); K = 28;  Kp = 32;  break;
    case 4: src = Wq;         dst = (bf16*)(wsb + OFF_WT_Q);     K = 256; Kp = 256; break;
    case 5: src = Wk;         dst = (bf16*)(wsb + OFF_WT_K);     K = 256; Kp = 256; chunked = true; break;
    case 6: src = Wv;         dst = (bf16*)(wsb + OFF_WT_V1);    K = 256; Kp = 256; chunked = true; break;
    case 7: src = Wv + 65536; dst = (bf16*)(wsb + OFF_WT_V2);    K = 256; Kp = 256; break;
    case 8: src = Wa;         dst = (bf16*)(wsb + OFF_WT_A1);    K = 256; Kp = 256; break;
    default: src = Wa + 65536; dst = (bf16*)(wsb + OFF_WT_A2);   K = 256; Kp = 256; break;
  }
  int total = 256 * Kp;
  if (chunked) {
    for (int i = blockIdx.x * 256 + threadIdx.x; i < total; i += gridDim.x * 256) {
      int ch = i >> 13, n = (i >> 5) & 255, kk = i & 31;
      int k = ch * 32 + kk;
      dst[i] = (bf16)src[k * 256 + n];
    }
  } else {
    for (int i = blockIdx.x * 256 + threadIdx.x; i < total; i += gridDim.x * 256) {
      int n = i / Kp, k = i - n * Kp;
      dst[i] = (k < K) ? (bf16)src[k * 256 + n] : (bf16)0.f;
    }
  }
}

// ---------------------------------------------------------------------------
// Generic GEMM, BK=32, 64 rows x 128 cols per block (exact round-8 version).
// ---------------------------------------------------------------------------
template<int EMODE, bool AF32>
__global__ __launch_bounds__(256, 2) void gemm_k(
    const void* __restrict__ Aptr, const void* __restrict__ A2ptr,
    int lda, int K, int Klimit,
    const bf16* __restrict__ Wt, const bf16* __restrict__ Wt2,
    const float* __restrict__ bias, const float* __restrict__ bias2,
    const float* __restrict__ epsp, void* __restrict__ outp)
{
  constexpr bool DUALB = (EMODE == 0);
  constexpr bool DUALA = (EMODE == 3);
  __shared__ bf16 ldsA[64 * 40];
  __shared__ bf16 ldsB[128 * 40];
  __shared__ bf16 ldsB2[DUALB ? 128 * 40 : 8];

  const int tid = threadIdx.x;
  const int wave = tid >> 6;
  const int lane = tid & 63;
  const int quad = lane >> 4;
  const int m = lane & 15;
  const int rowbase = blockIdx.x * 64;
  const int colbase = blockIdx.y * 128;

  f32x4 acc[8];
  f32x4 accB[DUALB ? 8 : 1];
  const f32x4 z4 = {0.f, 0.f, 0.f, 0.f};
#pragma unroll
  for (int ct = 0; ct < 8; ++ct) acc[ct] = z4;
  if constexpr (DUALB) {
#pragma unroll
    for (int ct = 0; ct < 8; ++ct) accB[ct] = z4;
  }

  const int npass = DUALA ? 2 : 1;
  for (int pass = 0; pass < npass; ++pass) {
    const void* Ap = (pass == 0) ? Aptr : A2ptr;
    const bf16* Wp = (pass == 0) ? Wt : Wt2;
    for (int kc = 0; kc < K; kc += 32) {
      __syncthreads();
      if constexpr (AF32) {
        const float* Af = (const float*)Ap;
#pragma unroll
        for (int it = 0; it < 2; ++it) {
          int p = tid + 256 * it;          // 512 float4 segments (64 rows x 8)
          int r = p >> 3, fs = p & 7;
          int k = kc + fs * 4;
          const float* src = Af + (size_t)(rowbase + r) * lda + k;
          float v0, v1, v2, v3;
          if (k + 4 <= Klimit) {
            float4 v = *(const float4*)src;
            v0 = v.x; v1 = v.y; v2 = v.z; v3 = v.w;
          } else {
            v0 = (k + 0 < Klimit) ? src[0] : 0.f;
            v1 = (k + 1 < Klimit) ? src[1] : 0.f;
            v2 = (k + 2 < Klimit) ? src[2] : 0.f;
            v3 = (k + 3 < Klimit) ? src[3] : 0.f;
          }
          bf16x4 o = {(bf16)v0, (bf16)v1, (bf16)v2, (bf16)v3};
          *(bf16x4*)(ldsA + r * 40 + fs * 4) = o;
        }
      } else {
        const bf16* Ab = (const bf16*)Ap;
        {
          int p = tid;                      // 256 bf16x8 segments (64 rows x 4)
          int r = p >> 2, f = p & 3;
          *(bf16x8*)(ldsA + r * 40 + f * 8) =
              *(const bf16x8*)(Ab + (size_t)(rowbase + r) * lda + kc + f * 8);
        }
      }
#pragma unroll
      for (int it = 0; it < 2; ++it) {
        int p = tid + 256 * it;             // 512 bf16x8 segments (128 rows x 4)
        int n = p >> 2, f = p & 3;
        *(bf16x8*)(ldsB + n * 40 + f * 8) =
            *(const bf16x8*)(Wt + (size_t)(colbase + n) * K + kc + f * 8);
      }
      if constexpr (DUALB) {
#pragma unroll
        for (int it = 0; it < 2; ++it) {
          int p = tid + 256 * it;
          int n = p >> 2, f = p & 3;
          *(bf16x8*)(ldsB2 + n * 40 + f * 8) =
              *(const bf16x8*)(Wt2 + (size_t)(colbase + n) * K + kc + f * 8);
        }
      }
      __syncthreads();
      bf16x8 afrag = *(const bf16x8*)(ldsA + (wave * 16 + m) * 40 + quad * 8);
#pragma unroll
      for (int ct = 0; ct < 8; ++ct) {
        bf16x8 bfrag = *(const bf16x8*)(ldsB + (ct * 16 + m) * 40 + quad * 8);
        acc[ct] = __builtin_amdgcn_mfma_f32_16x16x32_bf16(afrag, bfrag, acc[ct], 0, 0, 0);
        if constexpr (DUALB) {
          bf16x8 b2 = *(const bf16x8*)(ldsB2 + (ct * 16 + m) * 40 + quad * 8);
          accB[ct] = __builtin_amdgcn_mfma_f32_16x16x32_bf16(afrag, b2, accB[ct], 0, 0, 0);
        }
      }
      (void)Wp;
    }
  }
#pragma unroll
  for (int ct = 0; ct < 8; ++ct) {
    const int col = colbase + ct * 16 + m;
    const float bv = bias[col];
#pragma unroll
    for (int r = 0; r < 4; ++r) {
      const size_t row = (size_t)rowbase + wave * 16 + quad * 4 + r;
      float v = acc[ct][r] + bv;
      if constexpr (EMODE == 0) {
        float lv = accB[ct][r] + bias2[col];
        float zz = epsp[row * 256 + col] * __expf(0.5f * lv) + v;
        ((bf16*)outp)[row * 256 + col] = (bf16)zz;
      } else if constexpr (EMODE == 1) {
        ((bf16*)outp)[row * 256 + col] = (bf16)(v > 0.f ? v : 0.f);
      } else if constexpr (EMODE == 2) {
        ((bf16*)outp)[row * 256 + col] = (bf16)v;
      } else {
        ((float*)outp)[row * 256 + col] = (v > 0.f ? v : 0.f);
      }
    }
  }
}

// Dedicated dual-A GEMM (exact round-8 version)
template<bool UNUSED>
__global__ __launch_bounds__(256, 2) void gemm_dualA(
    const bf16* __restrict__ A1, const bf16* __restrict__ A2,
    const bf16* __restrict__ Wt1, const bf16* __restrict__ Wt2,
    const float* __restrict__ bias, float* __restrict__ outp)
{
  __shared__ bf16 ldsA[64 * 40];
  __shared__ bf16 ldsB[128 * 40];

  const int tid = threadIdx.x;
  const int wave = tid >> 6;
  const int lane = tid & 63;
  const int quad = lane >> 4;
  const int m = lane & 15;
  const int rowbase = blockIdx.x * 64;
  const int colbase = blockIdx.y * 128;

  f32x4 acc[8];
  const f32x4 z4 = {0.f, 0.f, 0.f, 0.f};
#pragma unroll
  for (int ct = 0; ct < 8; ++ct) acc[ct] = z4;

  for (int pass = 0; pass < 2; ++pass) {
    const bf16* Ap = (pass == 0) ? A1 : A2;
    const bf16* Wp = (pass == 0) ? Wt1 : Wt2;
    for (int kc = 0; kc < 256; kc += 32) {
      __syncthreads();
      {
        int p = tid;
        int r = p >> 2, f = p & 3;
        *(bf16x8*)(ldsA + r * 40 + f * 8) =
            *(const bf16x8*)(Ap + (size_t)(rowbase + r) * 256 + kc + f * 8);
      }
#pragma unroll
      for (int it = 0; it < 2; ++it) {
        int p = tid + 256 * it;
        int n = p >> 2, f = p & 3;
        *(bf16x8*)(ldsB + n * 40 + f * 8) =
            *(const bf16x8*)(Wp + (size_t)(colbase + n) * 256 + kc + f * 8);
      }
      __syncthreads();
      bf16x8 afrag = *(const bf16x8*)(ldsA + (wave * 16 + m) * 40 + quad * 8);
#pragma unroll
      for (int ct = 0; ct < 8; ++ct) {
        bf16x8 bfrag = *(const bf16x8*)(ldsB + (ct * 16 + m) * 40 + quad * 8);
        acc[ct] = __builtin_amdgcn_mfma_f32_16x16x32_bf16(afrag, bfrag, acc[ct], 0, 0, 0);
      }
    }
  }
#pragma unroll
  for (int ct = 0; ct < 8; ++ct) {
    const int col = colbase + ct * 16 + m;
    const float bv = bias[col];
#pragma unroll
    for (int r = 0; r < 4; ++r) {
      const size_t row = (size_t)rowbase + wave * 16 + quad * 4 + r;
      float v = acc[ct][r] + bv;
      outp[row * 256 + col] = (v > 0.f ? v : 0.f);
    }
  }
}

// ---------------------------------------------------------------------------
// Fused attention -- round-8 LDS layout; ROUND-9 CHANGE: row-tile GROUPING
// in the K and V passes (groups {0,1},{2,3},{4}) so peak live accumulators
// drop 80->32 regs and fit the (256,3) budget of ~168 VGPRs spill-free
// (round 8 spilled 76 MB of scratch).  B-frags are re-read 3x per pass from
// L2-hot chunk-major weights (~12 us aggregate).  All group indices are
// compile-time (unrolled literal loops) so part[]/hacc[] stay in registers.
// ---------------------------------------------------------------------------
__global__ __launch_bounds__(256, 3) void k_fused(
    const float* __restrict__ x, const bf16* __restrict__ qb,
    const bf16* __restrict__ svb,
    const bf16* __restrict__ WtOther, const float* __restrict__ b_other,
    const bf16* __restrict__ WtKc, const float* __restrict__ b_k,
    const bf16* __restrict__ WtVc,
    float* __restrict__ att_out, bf16* __restrict__ hb)
{
  __shared__ bf16 ldsO[80 * 264];     // 42240 B  other_em (16B-group stride 33)
  __shared__ bf16 ldsA1[80 * 40];     //  6400 B  agents tile; REUSED: spart/attl
  __shared__ bf16 qh16[1024];         //  2048 B  q (bf16); REUSED: h partials
  __shared__ bf16 svl16[1024];        //  2048 B  sv (bf16)
  float* spart = (float*)ldsA1;        // [0..320)  floats: 4 waves x 80 rows
  float* attl  = (float*)ldsA1 + 320;  // [320..400) floats: att weights

  const int tid = threadIdx.x, wave = tid >> 6, lane = tid & 63;
  const int quad = lane >> 4, m = lane & 15;
  const int b0 = blockIdx.x * 4;

  // ---- phase 0: stage q, sv (bf16 copies), agents_info
  for (int i = tid; i < 512; i += 256) {
    ((unsigned*)qh16)[i]  = ((const unsigned*)(qb  + (size_t)b0 * 256))[i];
    ((unsigned*)svl16)[i] = ((const unsigned*)(svb + (size_t)b0 * 256))[i];
  }
  for (int i = tid; i < 80 * 16; i += 256) {
    int r = i >> 4, kk = (i & 15) * 2;
    float v0 = 0.f, v1 = 0.f;
    if (r < 76) {
      int bb = b0 + r / 19, n = r % 19;
      const float* base = x + (size_t)bb * NOBS + 36 + n * 28;
      if (kk < 28) v0 = base[kk];
      if (kk + 1 < 28) v1 = base[kk + 1];
    }
    unsigned u0 = bfbits(v0), u1 = bfbits(v1);
    *(unsigned*)(ldsA1 + r * 40 + kk) = u0 | (u1 << 16);
  }
  __syncthreads();

  const f32x4 z4 = {0.f, 0.f, 0.f, 0.f};

  // ---- phase 1: other_em = relu(A1 @ WtOther^T + b_other), K=32
  {
    f32x4 acc1[5][4];
    bf16x8 bfr[4];
#pragma unroll
    for (int c = 0; c < 4; ++c)
      bfr[c] = *(const bf16x8*)(WtOther + ((4 * wave + c) * 16 + m) * 32 + quad * 8);
#pragma unroll
    for (int rt = 0; rt < 5; ++rt) {
      bf16x8 a = *(const bf16x8*)(ldsA1 + (rt * 16 + m) * 40 + quad * 8);
#pragma unroll
      for (int c = 0; c < 4; ++c)
        acc1[rt][c] = __builtin_amdgcn_mfma_f32_16x16x32_bf16(a, bfr[c], z4, 0, 0, 0);
    }
#pragma unroll
    for (int rt = 0; rt < 5; ++rt)
#pragma unroll
      for (int c = 0; c < 4; ++c) {
        int col = (4 * wave + c) * 16 + m;
        float bv = b_other[col];
#pragma unroll
        for (int r = 0; r < 4; ++r) {
          float v = acc1[rt][c][r] + bv;
          v = v > 0.f ? v : 0.f;
          unsigned u = bfbits(v);
          unsigned other = (unsigned)__shfl_xor((int)u, 1, 64);
          if ((m & 1) == 0) {
            int rowl = rt * 16 + quad * 4 + r;
            *(unsigned*)(ldsO + rowl * 264 + col) = u | (other << 16);
          }
        }
      }
  }
  __syncthreads();   // ldsA1 (agents tile) dead from here; spart/attl overlay

  // ---- pass K (row-tile groups of 2): k-accumulate, barrier-free
  {
    float part[5][4];
#pragma unroll
    for (int rt = 0; rt < 5; ++rt)
#pragma unroll
      for (int r = 0; r < 4; ++r) part[rt][r] = 0.f;

#pragma unroll
    for (int g = 0; g < 3; ++g) {
      const int rt0 = 2 * g;
      const int nrt = (g == 2) ? 1 : 2;
      f32x4 aK[2][4];
#pragma unroll
      for (int t = 0; t < 2; ++t)
#pragma unroll
        for (int c = 0; c < 4; ++c) aK[t][c] = z4;

#pragma unroll
      for (int ch = 0; ch < 8; ++ch) {
        const int kc = ch * 32;
        bf16x8 bK[4];
#pragma unroll
        for (int c = 0; c < 4; ++c)
          bK[c] = *(const bf16x8*)(WtKc + (size_t)ch * 8192 + ((4 * wave + c) * 16 + m) * 32 + quad * 8);
#pragma unroll
        for (int t = 0; t < 2; ++t) {
          if (t < nrt) {
            bf16x8 a = *(const bf16x8*)(ldsO + ((rt0 + t) * 16 + m) * 264 + kc + quad * 8);
#pragma unroll
            for (int c = 0; c < 4; ++c)
              aK[t][c] = __builtin_amdgcn_mfma_f32_16x16x32_bf16(a, bK[c], aK[t][c], 0, 0, 0);
          }
        }
      }
      // fold this group into running score partials
#pragma unroll
      for (int t = 0; t < 2; ++t) {
        if (t < nrt) {
#pragma unroll
          for (int c = 0; c < 4; ++c) {
            int col = (4 * wave + c) * 16 + m;
            float bkv = b_k[col];
#pragma unroll
            for (int r = 0; r < 4; ++r) {
              int rowl = (rt0 + t) * 16 + quad * 4 + r;
              int br = rowl / 19; int bs = br > 3 ? 3 : br;
              float kv = aK[t][c][r] + bkv;
              kv = kv > 0.f ? kv : 0.f;
              part[rt0 + t][r] += kv * (float)qh16[bs * 256 + col];
            }
          }
        }
      }
    }

#pragma unroll
    for (int rt = 0; rt < 5; ++rt)
#pragma unroll
      for (int r = 0; r < 4; ++r) {
        float p = part[rt][r];
        p += __shfl_xor(p, 1, 64);
        p += __shfl_xor(p, 2, 64);
        p += __shfl_xor(p, 4, 64);
        p += __shfl_xor(p, 8, 64);
        if (m == 0) spart[wave * 80 + rt * 16 + quad * 4 + r] = p;
      }
  }
  __syncthreads();
  if (tid < 4) {
    float sc[19];
    float mx = -1e30f;
#pragma unroll
    for (int j = 0; j < 19; ++j) {
      int row = tid * 19 + j;
      float s = (spart[row] + spart[80 + row] + spart[160 + row] + spart[240 + row]) * 0.0625f;
      sc[j] = s; mx = fmaxf(mx, s);
    }
    float sum = 0.f;
#pragma unroll
    for (int j = 0; j < 19; ++j) { float e = __expf(sc[j] - mx); sc[j] = e; sum += e; }
    float inv = 1.f / sum;
#pragma unroll
    for (int j = 0; j < 19; ++j) {
      float a = sc[j] * inv;
      attl[tid * 19 + j] = a;
      att_out[(size_t)(b0 + tid) * 19 + j] = a;
    }
  }
  __syncthreads();

  // ---- pass V (row-tile groups of 2): v-accumulate, fold into h partials
  {
    float hacc[4][4];   // [c][batch]
#pragma unroll
    for (int c = 0; c < 4; ++c)
#pragma unroll
      for (int bb = 0; bb < 4; ++bb) hacc[c][bb] = 0.f;

#pragma unroll
    for (int g = 0; g < 3; ++g) {
      const int rt0 = 2 * g;
      const int nrt = (g == 2) ? 1 : 2;
      f32x4 aV[2][4];
#pragma unroll
      for (int t = 0; t < 2; ++t)
#pragma unroll
        for (int c = 0; c < 4; ++c) aV[t][c] = z4;

#pragma unroll
      for (int ch = 0; ch < 8; ++ch) {
        const int kc = ch * 32;
        bf16x8 bV[4];
#pragma unroll
        for (int c = 0; c < 4; ++c)
          bV[c] = *(const bf16x8*)(WtVc + (size_t)ch * 8192 + ((4 * wave + c) * 16 + m) * 32 + quad * 8);
#pragma unroll
        for (int t = 0; t < 2; ++t) {
          if (t < nrt) {
            bf16x8 a = *(const bf16x8*)(ldsO + ((rt0 + t) * 16 + m) * 264 + kc + quad * 8);
#pragma unroll
            for (int c = 0; c < 4; ++c)
              aV[t][c] = __builtin_amdgcn_mfma_f32_16x16x32_bf16(a, bV[c], aV[t][c], 0, 0, 0);
          }
        }
      }
      // fold this group: +sv, relu, *att, bucket into per-batch h
#pragma unroll
      for (int t = 0; t < 2; ++t) {
        if (t < nrt) {
#pragma unroll
          for (int c = 0; c < 4; ++c) {
            int col = (4 * wave + c) * 16 + m;
#pragma unroll
            for (int r = 0; r < 4; ++r) {
              int rowl = (rt0 + t) * 16 + quad * 4 + r;
              int br = rowl / 19; int bs = br > 3 ? 3 : br;
              float v = aV[t][c][r] + (float)svl16[bs * 256 + col];
              v = v > 0.f ? v : 0.f;
              int ai = bs * 19 + (rowl - bs * 19);   // valid rows: ai <= 75
              float hv = v * attl[ai < 76 ? ai : 75];
#pragma unroll
              for (int bb = 0; bb < 4; ++bb)
                hacc[c][bb] += (br == bb) ? hv : 0.f;
            }
          }
        }
      }
    }
    __syncthreads();   // all qh16 (q) readers done before h-partial overwrite
#pragma unroll
    for (int c = 0; c < 4; ++c)
#pragma unroll
      for (int bb = 0; bb < 4; ++bb) {
        float h = hacc[c][bb];
        h += __shfl_xor(h, 16, 64);
        h += __shfl_xor(h, 32, 64);
        if (quad == 0) qh16[bb * 256 + (4 * wave + c) * 16 + m] = (bf16)h;
      }
  }
  __syncthreads();
  for (int i = tid; i < 512; i += 256)
    ((unsigned*)(hb + (size_t)b0 * 256))[i] = ((const unsigned*)qh16)[i];
}

// ---------------------------------------------------------------------------
extern "C" void kernel_launch(void* const* d_in, const int* in_sizes, int n_in,
                              void* d_out, int out_size, void* d_ws, size_t ws_size,
                              hipStream_t stream) {
  (void)in_sizes; (void)n_in; (void)out_size; (void)ws_size;
  const float* x      = (const float*)d_in[0];
  const float* eps    = (const float*)d_in[1];
  const float* W_mu   = (const float*)d_in[2];
  const float* b_mu   = (const float*)d_in[3];
  const float* W_var  = (const float*)d_in[4];
  const float* b_var  = (const float*)d_in[5];
  const float* W_self = (const float*)d_in[6];
  const float* b_self = (const float*)d_in[7];
  const float* W_other= (const float*)d_in[8];
  const float* b_other= (const float*)d_in[9];
  const float* W_q    = (const float*)d_in[10];
  const float* b_q    = (const float*)d_in[11];
  const float* W_k    = (const float*)d_in[12];
  const float* b_k    = (const float*)d_in[13];
  const float* W_v    = (const float*)d_in[14];
  const float* b_v    = (const float*)d_in[15];
  const float* W_a    = (const float*)d_in[16];
  const float* b_a    = (const float*)d_in[17];

  char* wsb = (char*)d_ws;
  bf16* WtMu    = (bf16*)(wsb + OFF_WT_MU);
  bf16* WtVar   = (bf16*)(wsb + OFF_WT_VAR);
  bf16* WtSelf  = (bf16*)(wsb + OFF_WT_SELF);
  bf16* WtOther = (bf16*)(wsb + OFF_WT_OTHER);
  bf16* WtQ     = (bf16*)(wsb + OFF_WT_Q);
  bf16* WtK     = (bf16*)(wsb + OFF_WT_K);
  bf16* WtV1    = (bf16*)(wsb + OFF_WT_V1);
  bf16* WtV2    = (bf16*)(wsb + OFF_WT_V2);
  bf16* WtA1    = (bf16*)(wsb + OFF_WT_A1);
  bf16* WtA2    = (bf16*)(wsb + OFF_WT_A2);
  bf16* zbuf    = (bf16*)(wsb + OFF_Z);
  bf16* selfbuf = (bf16*)(wsb + OFF_SELF);
  bf16* qbuf    = (bf16*)(wsb + OFF_Q);
  bf16* svbuf   = (bf16*)(wsb + OFF_SV);
  bf16* hbuf    = (bf16*)(wsb + OFF_H);

  float* out = (float*)d_out;
  float* att_out = out + (size_t)NB * 256;

  dim3 blk(256);
  dim3 ggrid(NB / 64, 2);
  wprep<<<dim3(160, 10), blk, 0, stream>>>(W_mu, W_var, W_self, W_other, W_q, W_k, W_v, W_a, wsb);
  // z = eps*exp(0.5*logvar)+mu  (fused mu/var GEMM, K=576)
  gemm_k<0, true><<<ggrid, blk, 0, stream>>>(x, nullptr, 568, 576, 568,
                                             WtMu, WtVar, b_mu, b_var, eps, zbuf);
  // self_em = relu(x[:, :36] @ W_self + b_self)  (K=64, zero-padded weights)
  gemm_k<1, true><<<ggrid, blk, 0, stream>>>(x, nullptr, 568, 64, 568,
                                             WtSelf, nullptr, b_self, nullptr, nullptr, selfbuf);
  // q = relu(z @ W_q + b_q)
  gemm_k<1, false><<<ggrid, blk, 0, stream>>>(zbuf, nullptr, 256, 256, 256,
                                              WtQ, nullptr, b_q, nullptr, nullptr, qbuf);
  // sv = self_em @ W_v[256:] + b_v   (no relu)
  gemm_k<2, false><<<ggrid, blk, 0, stream>>>(selfbuf, nullptr, 256, 256, 256,
                                              WtV2, nullptr, b_v, nullptr, nullptr, svbuf);
  // fused: other_em -> k -> scores -> softmax -> v -> h
  k_fused<<<NB / 4, blk, 0, stream>>>(x, qbuf, svbuf, WtOther, b_other, WtK, b_k,
                                      WtV1, att_out, hbuf);
  // out = relu([h; self_em] @ W_a + b_a)   (dedicated dual-A kernel)
  gemm_dualA<true><<<ggrid, blk, 0, stream>>>(hbuf, selfbuf, WtA1, WtA2, b_a, out);
}

// Round 10
// 345.827 us; speedup vs baseline: 1.2286x; 1.2286x over previous
//
#include <hip/hip_runtime.h>

typedef __bf16 bf16;
typedef __bf16 bf16x4 __attribute__((ext_vector_type(4)));
typedef __bf16 bf16x8 __attribute__((ext_vector_type(8)));
typedef float  f32x4  __attribute__((ext_vector_type(4)));

// Problem constants
#define NB    16384      // batch
#define NOBS  568
#define NH    256
#define NAG   19         // N_OTHER

// ws byte offsets (all 16B aligned)
#define OFF_WT_MU    0u          // [256][576] bf16 (flat [n][kpad])
#define OFF_WT_VAR   294912u     // [256][576]
#define OFF_WT_SELF  589824u     // [256][64]
#define OFF_WT_OTHER 622592u     // [256][32]  (chunk-major == flat at K=32)
#define OFF_WT_Q     638976u     // [256][256] flat
#define OFF_WT_K     770048u     // CHUNK-MAJOR [8][256][32]
#define OFF_WT_V1    901120u     // CHUNK-MAJOR [8][256][32]
#define OFF_WT_V2    1032192u    // flat
#define OFF_WT_A1    1163264u    // flat
#define OFF_WT_A2    1294336u    // flat
#define OFF_Z        1425408u    // [16384][256] bf16
#define OFF_SELF     9814016u
#define OFF_Q        18202624u
#define OFF_SV       26591232u   // bf16 (includes b_v)
#define OFF_H        34979840u

static __device__ __forceinline__ unsigned short bfbits(float v) {
  bf16 b = (bf16)v;
  union { bf16 b; unsigned short u; } cvt; cvt.b = b; return cvt.u;
}

// ---------------------------------------------------------------------------
// Weight prep (exact round-8 version).
// ---------------------------------------------------------------------------
__global__ __launch_bounds__(256) void wprep(
    const float* __restrict__ Wmu, const float* __restrict__ Wvar,
    const float* __restrict__ Wself, const float* __restrict__ Wother,
    const float* __restrict__ Wq, const float* __restrict__ Wk,
    const float* __restrict__ Wv, const float* __restrict__ Wa, char* wsb)
{
  const float* src; bf16* dst; int K, Kp; bool chunked = false;
  switch (blockIdx.y) {
    case 0: src = Wmu;        dst = (bf16*)(wsb + OFF_WT_MU);    K = 568; Kp = 576; break;
    case 1: src = Wvar;       dst = (bf16*)(wsb + OFF_WT_VAR);   K = 568; Kp = 576; break;
    case 2: src = Wself;      dst = (bf16*)(wsb + OFF_WT_SELF);  K = 36;  Kp = 64;  break;
    case 3: src = Wother;     dst = (bf16*)(wsb + OFF_WT_OTHER); K = 28;  Kp = 32;  break;
    case 4: src = Wq;         dst = (bf16*)(wsb + OFF_WT_Q);     K = 256; Kp = 256; break;
    case 5: src = Wk;         dst = (bf16*)(wsb + OFF_WT_K);     K = 256; Kp = 256; chunked = true; break;
    case 6: src = Wv;         dst = (bf16*)(wsb + OFF_WT_V1);    K = 256; Kp = 256; chunked = true; break;
    case 7: src = Wv + 65536; dst = (bf16*)(wsb + OFF_WT_V2);    K = 256; Kp = 256; break;
    case 8: src = Wa;         dst = (bf16*)(wsb + OFF_WT_A1);    K = 256; Kp = 256; break;
    default: src = Wa + 65536; dst = (bf16*)(wsb + OFF_WT_A2);   K = 256; Kp = 256; break;
  }
  int total = 256 * Kp;
  if (chunked) {
    for (int i = blockIdx.x * 256 + threadIdx.x; i < total; i += gridDim.x * 256) {
      int ch = i >> 13, n = (i >> 5) & 255, kk = i & 31;
      int k = ch * 32 + kk;
      dst[i] = (bf16)src[k * 256 + n];
    }
  } else {
    for (int i = blockIdx.x * 256 + threadIdx.x; i < total; i += gridDim.x * 256) {
      int n = i / Kp, k = i - n * Kp;
      dst[i] = (k < K) ? (bf16)src[k * 256 + n] : (bf16)0.f;
    }
  }
}

// ---------------------------------------------------------------------------
// Generic GEMM, BK=32, 64 rows x 128 cols per block (exact round-8 version).
// ---------------------------------------------------------------------------
template<int EMODE, bool AF32>
__global__ __launch_bounds__(256, 2) void gemm_k(
    const void* __restrict__ Aptr, const void* __restrict__ A2ptr,
    int lda, int K, int Klimit,
    const bf16* __restrict__ Wt, const bf16* __restrict__ Wt2,
    const float* __restrict__ bias, const float* __restrict__ bias2,
    const float* __restrict__ epsp, void* __restrict__ outp)
{
  constexpr bool DUALB = (EMODE == 0);
  constexpr bool DUALA = (EMODE == 3);
  __shared__ bf16 ldsA[64 * 40];
  __shared__ bf16 ldsB[128 * 40];
  __shared__ bf16 ldsB2[DUALB ? 128 * 40 : 8];

  const int tid = threadIdx.x;
  const int wave = tid >> 6;
  const int lane = tid & 63;
  const int quad = lane >> 4;
  const int m = lane & 15;
  const int rowbase = blockIdx.x * 64;
  const int colbase = blockIdx.y * 128;

  f32x4 acc[8];
  f32x4 accB[DUALB ? 8 : 1];
  const f32x4 z4 = {0.f, 0.f, 0.f, 0.f};
#pragma unroll
  for (int ct = 0; ct < 8; ++ct) acc[ct] = z4;
  if constexpr (DUALB) {
#pragma unroll
    for (int ct = 0; ct < 8; ++ct) accB[ct] = z4;
  }

  const int npass = DUALA ? 2 : 1;
  for (int pass = 0; pass < npass; ++pass) {
    const void* Ap = (pass == 0) ? Aptr : A2ptr;
    const bf16* Wp = (pass == 0) ? Wt : Wt2;
    for (int kc = 0; kc < K; kc += 32) {
      __syncthreads();
      if constexpr (AF32) {
        const float* Af = (const float*)Ap;
#pragma unroll
        for (int it = 0; it < 2; ++it) {
          int p = tid + 256 * it;          // 512 float4 segments (64 rows x 8)
          int r = p >> 3, fs = p & 7;
          int k = kc + fs * 4;
          const float* src = Af + (size_t)(rowbase + r) * lda + k;
          float v0, v1, v2, v3;
          if (k + 4 <= Klimit) {
            float4 v = *(const float4*)src;
            v0 = v.x; v1 = v.y; v2 = v.z; v3 = v.w;
          } else {
            v0 = (k + 0 < Klimit) ? src[0] : 0.f;
            v1 = (k + 1 < Klimit) ? src[1] : 0.f;
            v2 = (k + 2 < Klimit) ? src[2] : 0.f;
            v3 = (k + 3 < Klimit) ? src[3] : 0.f;
          }
          bf16x4 o = {(bf16)v0, (bf16)v1, (bf16)v2, (bf16)v3};
          *(bf16x4*)(ldsA + r * 40 + fs * 4) = o;
        }
      } else {
        const bf16* Ab = (const bf16*)Ap;
        {
          int p = tid;                      // 256 bf16x8 segments (64 rows x 4)
          int r = p >> 2, f = p & 3;
          *(bf16x8*)(ldsA + r * 40 + f * 8) =
              *(const bf16x8*)(Ab + (size_t)(rowbase + r) * lda + kc + f * 8);
        }
      }
#pragma unroll
      for (int it = 0; it < 2; ++it) {
        int p = tid + 256 * it;             // 512 bf16x8 segments (128 rows x 4)
        int n = p >> 2, f = p & 3;
        *(bf16x8*)(ldsB + n * 40 + f * 8) =
            *(const bf16x8*)(Wt + (size_t)(colbase + n) * K + kc + f * 8);
      }
      if constexpr (DUALB) {
#pragma unroll
        for (int it = 0; it < 2; ++it) {
          int p = tid + 256 * it;
          int n = p >> 2, f = p & 3;
          *(bf16x8*)(ldsB2 + n * 40 + f * 8) =
              *(const bf16x8*)(Wt2 + (size_t)(colbase + n) * K + kc + f * 8);
        }
      }
      __syncthreads();
      bf16x8 afrag = *(const bf16x8*)(ldsA + (wave * 16 + m) * 40 + quad * 8);
#pragma unroll
      for (int ct = 0; ct < 8; ++ct) {
        bf16x8 bfrag = *(const bf16x8*)(ldsB + (ct * 16 + m) * 40 + quad * 8);
        acc[ct] = __builtin_amdgcn_mfma_f32_16x16x32_bf16(afrag, bfrag, acc[ct], 0, 0, 0);
        if constexpr (DUALB) {
          bf16x8 b2 = *(const bf16x8*)(ldsB2 + (ct * 16 + m) * 40 + quad * 8);
          accB[ct] = __builtin_amdgcn_mfma_f32_16x16x32_bf16(afrag, b2, accB[ct], 0, 0, 0);
        }
      }
      (void)Wp;
    }
  }
#pragma unroll
  for (int ct = 0; ct < 8; ++ct) {
    const int col = colbase + ct * 16 + m;
    const float bv = bias[col];
#pragma unroll
    for (int r = 0; r < 4; ++r) {
      const size_t row = (size_t)rowbase + wave * 16 + quad * 4 + r;
      float v = acc[ct][r] + bv;
      if constexpr (EMODE == 0) {
        float lv = accB[ct][r] + bias2[col];
        float zz = epsp[row * 256 + col] * __expf(0.5f * lv) + v;
        ((bf16*)outp)[row * 256 + col] = (bf16)zz;
      } else if constexpr (EMODE == 1) {
        ((bf16*)outp)[row * 256 + col] = (bf16)(v > 0.f ? v : 0.f);
      } else if constexpr (EMODE == 2) {
        ((bf16*)outp)[row * 256 + col] = (bf16)v;
      } else {
        ((float*)outp)[row * 256 + col] = (v > 0.f ? v : 0.f);
      }
    }
  }
}

// Dedicated dual-A GEMM (exact round-8 version)
template<bool UNUSED>
__global__ __launch_bounds__(256, 2) void gemm_dualA(
    const bf16* __restrict__ A1, const bf16* __restrict__ A2,
    const bf16* __restrict__ Wt1, const bf16* __restrict__ Wt2,
    const float* __restrict__ bias, float* __restrict__ outp)
{
  __shared__ bf16 ldsA[64 * 40];
  __shared__ bf16 ldsB[128 * 40];

  const int tid = threadIdx.x;
  const int wave = tid >> 6;
  const int lane = tid & 63;
  const int quad = lane >> 4;
  const int m = lane & 15;
  const int rowbase = blockIdx.x * 64;
  const int colbase = blockIdx.y * 128;

  f32x4 acc[8];
  const f32x4 z4 = {0.f, 0.f, 0.f, 0.f};
#pragma unroll
  for (int ct = 0; ct < 8; ++ct) acc[ct] = z4;

  for (int pass = 0; pass < 2; ++pass) {
    const bf16* Ap = (pass == 0) ? A1 : A2;
    const bf16* Wp = (pass == 0) ? Wt1 : Wt2;
    for (int kc = 0; kc < 256; kc += 32) {
      __syncthreads();
      {
        int p = tid;
        int r = p >> 2, f = p & 3;
        *(bf16x8*)(ldsA + r * 40 + f * 8) =
            *(const bf16x8*)(Ap + (size_t)(rowbase + r) * 256 + kc + f * 8);
      }
#pragma unroll
      for (int it = 0; it < 2; ++it) {
        int p = tid + 256 * it;
        int n = p >> 2, f = p & 3;
        *(bf16x8*)(ldsB + n * 40 + f * 8) =
            *(const bf16x8*)(Wp + (size_t)(colbase + n) * 256 + kc + f * 8);
      }
      __syncthreads();
      bf16x8 afrag = *(const bf16x8*)(ldsA + (wave * 16 + m) * 40 + quad * 8);
#pragma unroll
      for (int ct = 0; ct < 8; ++ct) {
        bf16x8 bfrag = *(const bf16x8*)(ldsB + (ct * 16 + m) * 40 + quad * 8);
        acc[ct] = __builtin_amdgcn_mfma_f32_16x16x32_bf16(afrag, bfrag, acc[ct], 0, 0, 0);
      }
    }
  }
#pragma unroll
  for (int ct = 0; ct < 8; ++ct) {
    const int col = colbase + ct * 16 + m;
    const float bv = bias[col];
#pragma unroll
    for (int r = 0; r < 4; ++r) {
      const size_t row = (size_t)rowbase + wave * 16 + quad * 4 + r;
      float v = acc[ct][r] + bv;
      outp[row * 256 + col] = (v > 0.f ? v : 0.f);
    }
  }
}

// ---------------------------------------------------------------------------
// Fused attention -- EXACT round-8 structure; ROUND-10 CHANGE (only one):
// `#pragma unroll 1` on both ch loops. Theory: at waves=3 (168-reg budget)
// the compiler fully unrolled ch and hoisted B-frag loads across iterations
// (up to 128 live load results) -> 76-220 MB scratch spill (rounds 8/9).
// Bounding unroll to 1 caps in-flight B-loads at one chunk (16 regs).
// ---------------------------------------------------------------------------
__global__ __launch_bounds__(256, 3) void k_fused(
    const float* __restrict__ x, const bf16* __restrict__ qb,
    const bf16* __restrict__ svb,
    const bf16* __restrict__ WtOther, const float* __restrict__ b_other,
    const bf16* __restrict__ WtKc, const float* __restrict__ b_k,
    const bf16* __restrict__ WtVc,
    float* __restrict__ att_out, bf16* __restrict__ hb)
{
  __shared__ bf16 ldsO[80 * 264];     // 42240 B  other_em (16B-group stride 33)
  __shared__ bf16 ldsA1[80 * 40];     //  6400 B  agents tile; REUSED: spart/attl
  __shared__ bf16 qh16[1024];         //  2048 B  q (bf16); REUSED: h partials
  __shared__ bf16 svl16[1024];        //  2048 B  sv (bf16)
  float* spart = (float*)ldsA1;        // [0..320)  floats: 4 waves x 80 rows
  float* attl  = (float*)ldsA1 + 320;  // [320..400) floats: att weights

  const int tid = threadIdx.x, wave = tid >> 6, lane = tid & 63;
  const int quad = lane >> 4, m = lane & 15;
  const int b0 = blockIdx.x * 4;

  // ---- phase 0: stage q, sv (bf16 copies), agents_info
  for (int i = tid; i < 512; i += 256) {
    ((unsigned*)qh16)[i]  = ((const unsigned*)(qb  + (size_t)b0 * 256))[i];
    ((unsigned*)svl16)[i] = ((const unsigned*)(svb + (size_t)b0 * 256))[i];
  }
  for (int i = tid; i < 80 * 16; i += 256) {
    int r = i >> 4, kk = (i & 15) * 2;
    float v0 = 0.f, v1 = 0.f;
    if (r < 76) {
      int bb = b0 + r / 19, n = r % 19;
      const float* base = x + (size_t)bb * NOBS + 36 + n * 28;
      if (kk < 28) v0 = base[kk];
      if (kk + 1 < 28) v1 = base[kk + 1];
    }
    unsigned u0 = bfbits(v0), u1 = bfbits(v1);
    *(unsigned*)(ldsA1 + r * 40 + kk) = u0 | (u1 << 16);
  }
  __syncthreads();

  const f32x4 z4 = {0.f, 0.f, 0.f, 0.f};

  // ---- phase 1: other_em = relu(A1 @ WtOther^T + b_other), K=32
  {
    f32x4 acc1[5][4];
    bf16x8 bfr[4];
#pragma unroll
    for (int c = 0; c < 4; ++c)
      bfr[c] = *(const bf16x8*)(WtOther + ((4 * wave + c) * 16 + m) * 32 + quad * 8);
#pragma unroll
    for (int rt = 0; rt < 5; ++rt) {
      bf16x8 a = *(const bf16x8*)(ldsA1 + (rt * 16 + m) * 40 + quad * 8);
#pragma unroll
      for (int c = 0; c < 4; ++c)
        acc1[rt][c] = __builtin_amdgcn_mfma_f32_16x16x32_bf16(a, bfr[c], z4, 0, 0, 0);
    }
#pragma unroll
    for (int rt = 0; rt < 5; ++rt)
#pragma unroll
      for (int c = 0; c < 4; ++c) {
        int col = (4 * wave + c) * 16 + m;
        float bv = b_other[col];
#pragma unroll
        for (int r = 0; r < 4; ++r) {
          float v = acc1[rt][c][r] + bv;
          v = v > 0.f ? v : 0.f;
          unsigned u = bfbits(v);
          unsigned other = (unsigned)__shfl_xor((int)u, 1, 64);
          if ((m & 1) == 0) {
            int rowl = rt * 16 + quad * 4 + r;
            *(unsigned*)(ldsO + rowl * 264 + col) = u | (other << 16);
          }
        }
      }
  }
  __syncthreads();   // ldsA1 (agents tile) dead from here; spart/attl overlay

  // ---- pass K: k-accumulate, barrier-free (B direct from global)
  {
    f32x4 aK[5][4];
#pragma unroll
    for (int rt = 0; rt < 5; ++rt)
#pragma unroll
      for (int c = 0; c < 4; ++c) aK[rt][c] = z4;

#pragma unroll 1
    for (int ch = 0; ch < 8; ++ch) {
      const int kc = ch * 32;
      bf16x8 bK[4];
#pragma unroll
      for (int c = 0; c < 4; ++c)
        bK[c] = *(const bf16x8*)(WtKc + (size_t)ch * 8192 + ((4 * wave + c) * 16 + m) * 32 + quad * 8);
#pragma unroll
      for (int rt = 0; rt < 5; ++rt) {
        bf16x8 a = *(const bf16x8*)(ldsO + (rt * 16 + m) * 264 + kc + quad * 8);
#pragma unroll
        for (int c = 0; c < 4; ++c)
          aK[rt][c] = __builtin_amdgcn_mfma_f32_16x16x32_bf16(a, bK[c], aK[rt][c], 0, 0, 0);
      }
    }

    // scores: relu(k)+b_k dot q, reduce across lanes then waves
#pragma unroll
    for (int rt = 0; rt < 5; ++rt) {
      float part[4] = {0.f, 0.f, 0.f, 0.f};
#pragma unroll
      for (int c = 0; c < 4; ++c) {
        int col = (4 * wave + c) * 16 + m;
        float bkv = b_k[col];
#pragma unroll
        for (int r = 0; r < 4; ++r) {
          int rowl = rt * 16 + quad * 4 + r;
          int br = rowl / 19; int bs = br > 3 ? 3 : br;
          float kv = aK[rt][c][r] + bkv;
          kv = kv > 0.f ? kv : 0.f;
          part[r] += kv * (float)qh16[bs * 256 + col];
        }
      }
#pragma unroll
      for (int r = 0; r < 4; ++r) {
        float p = part[r];
        p += __shfl_xor(p, 1, 64);
        p += __shfl_xor(p, 2, 64);
        p += __shfl_xor(p, 4, 64);
        p += __shfl_xor(p, 8, 64);
        if (m == 0) spart[wave * 80 + rt * 16 + quad * 4 + r] = p;
      }
    }
  }
  __syncthreads();
  if (tid < 4) {
    float sc[19];
    float mx = -1e30f;
#pragma unroll
    for (int j = 0; j < 19; ++j) {
      int row = tid * 19 + j;
      float s = (spart[row] + spart[80 + row] + spart[160 + row] + spart[240 + row]) * 0.0625f;
      sc[j] = s; mx = fmaxf(mx, s);
    }
    float sum = 0.f;
#pragma unroll
    for (int j = 0; j < 19; ++j) { float e = __expf(sc[j] - mx); sc[j] = e; sum += e; }
    float inv = 1.f / sum;
#pragma unroll
    for (int j = 0; j < 19; ++j) {
      float a = sc[j] * inv;
      attl[tid * 19 + j] = a;
      att_out[(size_t)(b0 + tid) * 19 + j] = a;
    }
  }
  __syncthreads();

  // ---- pass V: v-accumulate (same structure), then h epilogue
  {
    f32x4 aV[5][4];
#pragma unroll
    for (int rt = 0; rt < 5; ++rt)
#pragma unroll
      for (int c = 0; c < 4; ++c) aV[rt][c] = z4;

#pragma unroll 1
    for (int ch = 0; ch < 8; ++ch) {
      const int kc = ch * 32;
      bf16x8 bV[4];
#pragma unroll
      for (int c = 0; c < 4; ++c)
        bV[c] = *(const bf16x8*)(WtVc + (size_t)ch * 8192 + ((4 * wave + c) * 16 + m) * 32 + quad * 8);
#pragma unroll
      for (int rt = 0; rt < 5; ++rt) {
        bf16x8 a = *(const bf16x8*)(ldsO + (rt * 16 + m) * 264 + kc + quad * 8);
#pragma unroll
        for (int c = 0; c < 4; ++c)
          aV[rt][c] = __builtin_amdgcn_mfma_f32_16x16x32_bf16(a, bV[c], aV[rt][c], 0, 0, 0);
      }
    }

    // epilogue: +sv, relu, *att, bucket into per-batch h, reduce
    float hacc[4][4];   // [c][batch]
#pragma unroll
    for (int c = 0; c < 4; ++c)
#pragma unroll
      for (int bb = 0; bb < 4; ++bb) hacc[c][bb] = 0.f;
#pragma unroll
    for (int rt = 0; rt < 5; ++rt)
#pragma unroll
      for (int c = 0; c < 4; ++c) {
        int col = (4 * wave + c) * 16 + m;
#pragma unroll
        for (int r = 0; r < 4; ++r) {
          int rowl = rt * 16 + quad * 4 + r;
          int br = rowl / 19; int bs = br > 3 ? 3 : br;
          float v = aV[rt][c][r] + (float)svl16[bs * 256 + col];
          v = v > 0.f ? v : 0.f;
          int ai = bs * 19 + (rowl - bs * 19);   // valid rows: ai <= 75
          float hv = v * attl[ai < 76 ? ai : 75];
#pragma unroll
          for (int bb = 0; bb < 4; ++bb)
            hacc[c][bb] += (br == bb) ? hv : 0.f;
        }
      }
    __syncthreads();   // all qh16 (q) readers done before h-partial overwrite
#pragma unroll
    for (int c = 0; c < 4; ++c)
#pragma unroll
      for (int bb = 0; bb < 4; ++bb) {
        float h = hacc[c][bb];
        h += __shfl_xor(h, 16, 64);
        h += __shfl_xor(h, 32, 64);
        if (quad == 0) qh16[bb * 256 + (4 * wave + c) * 16 + m] = (bf16)h;
      }
  }
  __syncthreads();
  for (int i = tid; i < 512; i += 256)
    ((unsigned*)(hb + (size_t)b0 * 256))[i] = ((const unsigned*)qh16)[i];
}

// ---------------------------------------------------------------------------
extern "C" void kernel_launch(void* const* d_in, const int* in_sizes, int n_in,
                              void* d_out, int out_size, void* d_ws, size_t ws_size,
                              hipStream_t stream) {
  (void)in_sizes; (void)n_in; (void)out_size; (void)ws_size;
  const float* x      = (const float*)d_in[0];
  const float* eps    = (const float*)d_in[1];
  const float* W_mu   = (const float*)d_in[2];
  const float* b_mu   = (const float*)d_in[3];
  const float* W_var  = (const float*)d_in[4];
  const float* b_var  = (const float*)d_in[5];
  const float* W_self = (const float*)d_in[6];
  const float* b_self = (const float*)d_in[7];
  const float* W_other= (const float*)d_in[8];
  const float* b_other= (const float*)d_in[9];
  const float* W_q    = (const float*)d_in[10];
  const float* b_q    = (const float*)d_in[11];
  const float* W_k    = (const float*)d_in[12];
  const float* b_k    = (const float*)d_in[13];
  const float* W_v    = (const float*)d_in[14];
  const float* b_v    = (const float*)d_in[15];
  const float* W_a    = (const float*)d_in[16];
  const float* b_a    = (const float*)d_in[17];

  char* wsb = (char*)d_ws;
  bf16* WtMu    = (bf16*)(wsb + OFF_WT_MU);
  bf16* WtVar   = (bf16*)(wsb + OFF_WT_VAR);
  bf16* WtSelf  = (bf16*)(wsb + OFF_WT_SELF);
  bf16* WtOther = (bf16*)(wsb + OFF_WT_OTHER);
  bf16* WtQ     = (bf16*)(wsb + OFF_WT_Q);
  bf16* WtK     = (bf16*)(wsb + OFF_WT_K);
  bf16* WtV1    = (bf16*)(wsb + OFF_WT_V1);
  bf16* WtV2    = (bf16*)(wsb + OFF_WT_V2);
  bf16* WtA1    = (bf16*)(wsb + OFF_WT_A1);
  bf16* WtA2    = (bf16*)(wsb + OFF_WT_A2);
  bf16* zbuf    = (bf16*)(wsb + OFF_Z);
  bf16* selfbuf = (bf16*)(wsb + OFF_SELF);
  bf16* qbuf    = (bf16*)(wsb + OFF_Q);
  bf16* svbuf   = (bf16*)(wsb + OFF_SV);
  bf16* hbuf    = (bf16*)(wsb + OFF_H);

  float* out = (float*)d_out;
  float* att_out = out + (size_t)NB * 256;

  dim3 blk(256);
  dim3 ggrid(NB / 64, 2);
  wprep<<<dim3(160, 10), blk, 0, stream>>>(W_mu, W_var, W_self, W_other, W_q, W_k, W_v, W_a, wsb);
  // z = eps*exp(0.5*logvar)+mu  (fused mu/var GEMM, K=576)
  gemm_k<0, true><<<ggrid, blk, 0, stream>>>(x, nullptr, 568, 576, 568,
                                             WtMu, WtVar, b_mu, b_var, eps, zbuf);
  // self_em = relu(x[:, :36] @ W_self + b_self)  (K=64, zero-padded weights)
  gemm_k<1, true><<<ggrid, blk, 0, stream>>>(x, nullptr, 568, 64, 568,
                                             WtSelf, nullptr, b_self, nullptr, nullptr, selfbuf);
  // q = relu(z @ W_q + b_q)
  gemm_k<1, false><<<ggrid, blk, 0, stream>>>(zbuf, nullptr, 256, 256, 256,
                                              WtQ, nullptr, b_q, nullptr, nullptr, qbuf);
  // sv = self_em @ W_v[256:] + b_v   (no relu)
  gemm_k<2, false><<<ggrid, blk, 0, stream>>>(selfbuf, nullptr, 256, 256, 256,
                                              WtV2, nullptr, b_v, nullptr, nullptr, svbuf);
  // fused: other_em -> k -> scores -> softmax -> v -> h
  k_fused<<<NB / 4, blk, 0, stream>>>(x, qbuf, svbuf, WtOther, b_other, WtK, b_k,
                                      WtV1, att_out, hbuf);
  // out = relu([h; self_em] @ W_a + b_a)   (dedicated dual-A kernel)
  gemm_dualA<true><<<ggrid, blk, 0, stream>>>(hbuf, selfbuf, WtA1, WtA2, b_a, out);
}